// Round 8
// baseline (298.765 us; speedup 1.0000x reference)
//
#include <hip/hip_runtime.h>

#define NSEQ   16
#define KVH    8
#define NG     4      // query heads per kv head
#define HD     128
#define BS     16
#define MAXB   256
#define WPT    128    // tokens per item (one wave, 2 chains of 64)
#define NCHUNK 32     // items per (s,kvh)
#define NITEMS (NSEQ * KVH * NCHUNK)   // 4096
#define PSTRIDE 520   // floats per record: o[512], l[4], m, pad
#define REC_BYTES ((size_t)NITEMS * PSTRIDE * 4)
#define SCALE_F 0.08838834764831845f
#define NBLOCKS 512   // x256 thr = 2048 waves, ~8 blocks/CU target

// Kernel 1: WAVE-level work stealing, zero __syncthreads. Each wave grabs a
// 128-token item (lane-0 atomic, __shfl broadcast) and processes it fully
// wave-locally as TWO interleaved 64-token chains (independent load/FMA
// streams -> 2x memory-level parallelism per wave). Rationale: r4 counters
// (VALUBusy 22%, HBM 26%, 0 conflicts) + r7 (balance didn't help) => latency-
// bound with <1KB in flight per wave; more independent streams is the lever.
__global__ __launch_bounds__(256) void pa_partial_kernel(
    const float* __restrict__ query,
    const float* __restrict__ key,
    const float* __restrict__ value,
    const float* __restrict__ key_cache,
    const float* __restrict__ value_cache,
    const int*   __restrict__ block_tables,
    const int*   __restrict__ context_lens,
    float*       __restrict__ ws,
    unsigned int* __restrict__ counter)
{
    __shared__ float p_all[4][NG][WPT];   // per-wave probability tiles (8 KB)
    const int tid  = threadIdx.x;
    const int wv   = tid >> 6;
    const int lane = tid & 63;
    float* pw = &p_all[wv][0][0];         // this wave's [NG][WPT] tile

    for (;;) {
        int item;
        if (lane == 0) item = (int)atomicAdd(counter, 1u);
        item = __shfl(item, 0);           // wave broadcast
        if (item >= NITEMS) return;

        const int ck  = item & (NCHUNK - 1);
        const int kvh = (item >> 5) & (KVH - 1);
        const int s   = item >> 8;
        const int ctx = context_lens[s];
        const int t0  = ck * WPT;
        if (t0 >= ctx) continue;          // wave-uniform skip, no barriers involved

        const float*  q      = query + ((size_t)s * KVH + kvh) * (NG * HD);
        const size_t  kvhoff = (size_t)kvh * (HD * BS);

        // ---- QK: two independent 64-token chains ----
        const int tA  = t0 + lane;             // < 4096: all reads in-bounds
        const int tB  = t0 + 64 + lane;
        const int btA = block_tables[s * MAXB + (tA >> 4)];
        const int btB = block_tables[s * MAXB + (tB >> 4)];
        const float* kbA = key_cache + (size_t)btA * (KVH * HD * BS) + kvhoff + (tA & 15) * 8;
        const float* kbB = key_cache + (size_t)btB * (KVH * HD * BS) + kvhoff + (tB & 15) * 8;

        float scA[NG] = {0.f, 0.f, 0.f, 0.f};
        float scB[NG] = {0.f, 0.f, 0.f, 0.f};
        #pragma unroll
        for (int j = 0; j < 16; ++j) {
            const float4 a0 = *(const float4*)(kbA + j * 128);
            const float4 a1 = *(const float4*)(kbA + j * 128 + 4);
            const float4 b0 = *(const float4*)(kbB + j * 128);
            const float4 b1 = *(const float4*)(kbB + j * 128 + 4);
            #pragma unroll
            for (int g = 0; g < NG; ++g) {
                const float* qg = q + g * HD + j * 8;   // wave-uniform -> scalar path
                scA[g] += qg[0]*a0.x + qg[1]*a0.y + qg[2]*a0.z + qg[3]*a0.w
                        + qg[4]*a1.x + qg[5]*a1.y + qg[6]*a1.z + qg[7]*a1.w;
                scB[g] += qg[0]*b0.x + qg[1]*b0.y + qg[2]*b0.z + qg[3]*b0.w
                        + qg[4]*b1.x + qg[5]*b1.y + qg[6]*b1.z + qg[7]*b1.w;
            }
        }

        // new-token K correction: token ctx-1's key comes from the `key` input
        if (tA == ctx - 1) {
            const float4* kn4 = (const float4*)(key + ((size_t)s * KVH + kvh) * HD);
            float ns[NG] = {0.f, 0.f, 0.f, 0.f};
            #pragma unroll
            for (int c = 0; c < 32; ++c) {
                const float4 k4 = kn4[c];
                #pragma unroll
                for (int g = 0; g < NG; ++g) {
                    const float* qg = q + g * HD + c * 4;
                    ns[g] += qg[0]*k4.x + qg[1]*k4.y + qg[2]*k4.z + qg[3]*k4.w;
                }
            }
            #pragma unroll
            for (int g = 0; g < NG; ++g) scA[g] = ns[g];
        }
        if (tB == ctx - 1) {
            const float4* kn4 = (const float4*)(key + ((size_t)s * KVH + kvh) * HD);
            float ns[NG] = {0.f, 0.f, 0.f, 0.f};
            #pragma unroll
            for (int c = 0; c < 32; ++c) {
                const float4 k4 = kn4[c];
                #pragma unroll
                for (int g = 0; g < NG; ++g) {
                    const float* qg = q + g * HD + c * 4;
                    ns[g] += qg[0]*k4.x + qg[1]*k4.y + qg[2]*k4.z + qg[3]*k4.w;
                }
            }
            #pragma unroll
            for (int g = 0; g < NG; ++g) scB[g] = ns[g];
        }

        // ---- mask + wave-local softmax (shared max across heads is valid) ----
        float mv = -1e30f;
        if (tA < ctx) {
            #pragma unroll
            for (int g = 0; g < NG; ++g) { scA[g] *= SCALE_F; mv = fmaxf(mv, scA[g]); }
        } else {
            #pragma unroll
            for (int g = 0; g < NG; ++g) scA[g] = -1e30f;
        }
        if (tB < ctx) {
            #pragma unroll
            for (int g = 0; g < NG; ++g) { scB[g] *= SCALE_F; mv = fmaxf(mv, scB[g]); }
        } else {
            #pragma unroll
            for (int g = 0; g < NG; ++g) scB[g] = -1e30f;
        }
        #pragma unroll
        for (int o = 32; o; o >>= 1) mv = fmaxf(mv, __shfl_xor(mv, o));
        const float m_w = mv;

        float l[NG];
        #pragma unroll
        for (int g = 0; g < NG; ++g) {
            const float pA = __expf(scA[g] - m_w);   // exactly 0 for masked
            const float pB = __expf(scB[g] - m_w);
            pw[g * WPT + lane]      = pA;
            pw[g * WPT + 64 + lane] = pB;
            l[g] = pA + pB;
        }
        #pragma unroll
        for (int o = 32; o; o >>= 1) {
            l[0] += __shfl_xor(l[0], o);
            l[1] += __shfl_xor(l[1], o);
            l[2] += __shfl_xor(l[2], o);
            l[3] += __shfl_xor(l[3], o);
        }

        // ---- PV: lane = d, two d-halves, 8 token-blocks (skip fully-masked) ----
        const int nbv = min(8, (ctx - t0 + 15) >> 4);
        float a0[NG] = {0.f, 0.f, 0.f, 0.f};
        float a1[NG] = {0.f, 0.f, 0.f, 0.f};
        const float4* pl4 = (const float4*)pw;
        for (int b = 0; b < nbv; ++b) {
            const int btv = block_tables[s * MAXB + (t0 >> 4) + b];   // uniform
            const float* vb = value_cache + (size_t)btv * (KVH * HD * BS) + kvhoff;
            #pragma unroll
            for (int c = 0; c < 4; ++c) {
                const float4 v0 = *(const float4*)(vb + lane * BS + c * 4);
                const float4 v1 = *(const float4*)(vb + (lane + 64) * BS + c * 4);
                #pragma unroll
                for (int g = 0; g < NG; ++g) {
                    const float4 pg = pl4[g * (WPT / 4) + b * 4 + c];  // uniform -> broadcast
                    a0[g] += pg.x*v0.x + pg.y*v0.y + pg.z*v0.z + pg.w*v0.w;
                    a1[g] += pg.x*v1.x + pg.y*v1.y + pg.z*v1.z + pg.w*v1.w;
                }
            }
        }

        // new-token V correction: replace stale cache V at token ctx-1
        const int tl = ctx - 1 - t0;
        if (tl >= 0 && tl < WPT) {
            const int btn = block_tables[s * MAXB + ((ctx - 1) >> 4)];
            const float* vbn = value_cache + (size_t)btn * (KVH * HD * BS) + kvhoff
                             + ((ctx - 1) & 15);
            const float dv0 = value[((size_t)s * KVH + kvh) * HD + lane]
                            - vbn[lane * BS];
            const float dv1 = value[((size_t)s * KVH + kvh) * HD + lane + 64]
                            - vbn[(lane + 64) * BS];
            #pragma unroll
            for (int g = 0; g < NG; ++g) {
                a0[g] += pw[g * WPT + tl] * dv0;
                a1[g] += pw[g * WPT + tl] * dv1;
            }
        }

        // ---- write record (item-indexed -> deterministic output) ----
        float* rec = ws + (size_t)item * PSTRIDE;
        #pragma unroll
        for (int g = 0; g < NG; ++g) {
            rec[g * HD + lane]      = a0[g];
            rec[g * HD + 64 + lane] = a1[g];
        }
        if (lane == 0) {
            #pragma unroll
            for (int g = 0; g < NG; ++g) rec[512 + g] = l[g];
            rec[516] = m_w;
        }
    }
}

// Kernel 2: LSE-combine the <=32 partitions -> output. One (seq,kvh,g) per block.
__global__ __launch_bounds__(128) void pa_reduce_kernel(
    const float* __restrict__ ws,
    const int*   __restrict__ context_lens,
    float*       __restrict__ out)
{
    const int b    = blockIdx.x;        // ((s*KVH)+kvh)*NG + g
    const int g    = b & 3;
    const int pair = b >> 2;            // s*KVH + kvh
    const int s    = pair >> 3;
    const int kvh  = pair & 7;
    const int ctx  = context_lens[s];
    const int np   = (ctx + WPT - 1) / WPT;

    const int d = threadIdx.x;
    const float* base = ws + (size_t)pair * NCHUNK * PSTRIDE;

    float M = -1e30f;
    for (int p2 = 0; p2 < np; ++p2) M = fmaxf(M, base[p2 * PSTRIDE + 516]);

    float L = 0.f, acc = 0.f;
    for (int p2 = 0; p2 < np; ++p2) {
        const float* rec = base + p2 * PSTRIDE;
        const float w = __expf(rec[516] - M);
        L   += w * rec[512 + g];
        acc += w * rec[g * HD + d];
    }

    out[(size_t)s * (KVH * NG * HD) + (size_t)(kvh * NG + g) * HD + d] = acc / L;
}

extern "C" void kernel_launch(void* const* d_in, const int* in_sizes, int n_in,
                              void* d_out, int out_size, void* d_ws, size_t ws_size,
                              hipStream_t stream) {
    const float* query       = (const float*)d_in[0];
    const float* key         = (const float*)d_in[1];
    const float* value       = (const float*)d_in[2];
    const float* key_cache   = (const float*)d_in[3];
    const float* value_cache = (const float*)d_in[4];
    const int*   block_tables  = (const int*)d_in[5];
    const int*   context_lens  = (const int*)d_in[6];
    // d_in[7] slot_mapping unused: slot is derivable from context_lens + block_tables

    float* out = (float*)d_out;
    float* ws  = (float*)d_ws;   // records: 4096*520*4 = 8.52 MB, + 4 B counter
    unsigned int* counter = (unsigned int*)((char*)d_ws + REC_BYTES);

    hipMemsetAsync(counter, 0, sizeof(unsigned int), stream);
    pa_partial_kernel<<<NBLOCKS, 256, 0, stream>>>(
        query, key, value, key_cache, value_cache, block_tables, context_lens, ws, counter);
    pa_reduce_kernel<<<NSEQ * KVH * NG, 128, 0, stream>>>(ws, context_lens, out);
}

// Round 9
// 183.461 us; speedup vs baseline: 1.6285x; 1.6285x over previous
//
#include <hip/hip_runtime.h>

#define NSEQ   16
#define KVH    8
#define NG     4
#define HD     128
#define BS     16
#define MAXB   256
#define WPT    128    // tokens per item (one wave, 8 phys blocks)
#define NCHUNK 32     // items per (s,kvh)
#define NITEMS (NSEQ * KVH * NCHUNK)   // 4096
#define PSTRIDE 520   // floats per record: o[512], l[4], m, pad
#define REC_BYTES ((size_t)NITEMS * PSTRIDE * 4)
#define SCALE_F 0.08838834764831845f
#define NBLOCKS 1024  // 4 blocks/CU, 16 waves/CU

// Kernel 1: wave-level work stealing (r7 shell), but every global load is a
// FULLY CONTIGUOUS 1KB instruction (64 lanes x float4, zero line-touch
// amplification). Old mapping: K = 16B/lane @ 32B stride (2x line touches),
// V = 16B/lane @ 64B stride (4x). Evidence: ~4 TB/s demand wall across
// occupancy 8/16/32 waves-CU, balance, phases -> request-rate-limited.
// Lane roles after contiguous load:
//   K instr (block b, o): lane l holds K[j=o*2+(l>>5)][t=(l>>1)&15][x=(l&1)*4..+4]
//     -> partial dot, reduce shfl_xor(1)+shfl_xor(32)
//   V instr (block b, sub): lane l holds V[d=sub*16+(l>>2)][tq=(l&3)*4..+4]
//     -> dot with p4 from LDS, reduce shfl_xor(1)+shfl_xor(2)
__global__ __launch_bounds__(256, 3) void pa_partial_kernel(
    const float* __restrict__ query,
    const float* __restrict__ key,
    const float* __restrict__ value,
    const float* __restrict__ key_cache,
    const float* __restrict__ value_cache,
    const int*   __restrict__ block_tables,
    const int*   __restrict__ context_lens,
    float*       __restrict__ ws,
    unsigned int* __restrict__ counter)
{
    __shared__ float q_all[4][NG * HD];   // per-wave Q (2 KB each)
    __shared__ float p_all[4][NG * WPT];  // per-wave probabilities (2 KB each)

    const int tid  = threadIdx.x;
    const int wv   = tid >> 6;
    const int lane = tid & 63;
    float* qw = q_all[wv];
    float* pw = p_all[wv];

    const int t_me = (lane >> 1) & 15;    // K-phase token within block
    const int xh   = (lane & 1) * 4;      // K-phase x-offset
    const int jh   = (lane >> 5) * 8;     // K-phase j-offset (floats)

    for (;;) {
        int item;
        if (lane == 0) item = (int)atomicAdd(counter, 1u);
        item = __shfl(item, 0);
        if (item >= NITEMS) return;

        const int ck  = item & (NCHUNK - 1);
        const int kvh = (item >> 5) & (KVH - 1);
        const int s   = item >> 8;
        const int ctx = context_lens[s];
        const int t0  = ck * WPT;
        if (t0 >= ctx) continue;

        // ---- stage Q into this wave's LDS slice (no barrier: wave-local) ----
        const float* qsrc = query + (size_t)s * (KVH * NG * HD) + (size_t)kvh * (NG * HD);
        *(float4*)&qw[lane * 8]     = *(const float4*)(qsrc + lane * 8);
        *(float4*)&qw[lane * 8 + 4] = *(const float4*)(qsrc + lane * 8 + 4);

        // ---- per-block bases (contiguous-lane offsets folded in) ----
        const int b0 = t0 >> 4;
        const float* kbase[8];
        const float* vbase[8];
        int kstep[8];
        const float* keyl = key + ((size_t)s * KVH + kvh) * HD + jh + xh;  // lane's key slice
        #pragma unroll
        for (int b = 0; b < 8; ++b) {
            const int bt = block_tables[s * MAXB + b0 + b];
            const float* kc = key_cache   + (size_t)bt * (KVH * HD * BS)
                                          + (size_t)kvh * (HD * BS) + lane * 4;
            vbase[b]        = value_cache + (size_t)bt * (KVH * HD * BS)
                                          + (size_t)kvh * (HD * BS) + lane * 4;
            // new-token K: lanes covering token ctx-1 read from `key` instead
            const bool swap = (t0 + b * 16 + t_me) == (ctx - 1);
            kbase[b] = swap ? keyl : kc;
            kstep[b] = swap ? 16 : 256;   // floats per o-step (j advances by 2)
        }

        // ---- QK: 64 contiguous 1KB loads, partial dots ----
        float sc[NG][8];
        #pragma unroll
        for (int g = 0; g < NG; ++g)
            #pragma unroll
            for (int b = 0; b < 8; ++b) sc[g][b] = 0.f;

        #pragma unroll
        for (int o = 0; o < 8; ++o) {
            float4 q4[NG];
            #pragma unroll
            for (int g = 0; g < NG; ++g)
                q4[g] = *(const float4*)&qw[g * HD + o * 16 + jh + xh];
            #pragma unroll
            for (int b = 0; b < 8; ++b) {
                const float4 k4 = *(const float4*)(kbase[b] + o * kstep[b]);
                #pragma unroll
                for (int g = 0; g < NG; ++g)
                    sc[g][b] += q4[g].x * k4.x + q4[g].y * k4.y
                              + q4[g].z * k4.z + q4[g].w * k4.w;
            }
        }

        // ---- reduce partials (x-half, j-parity), mask, scale, max ----
        float mv = -1e30f;
        #pragma unroll
        for (int b = 0; b < 8; ++b) {
            const bool act = (t0 + b * 16 + t_me) < ctx;
            #pragma unroll
            for (int g = 0; g < NG; ++g) {
                float v = sc[g][b];
                v += __shfl_xor(v, 1);
                v += __shfl_xor(v, 32);
                v = act ? v * SCALE_F : -1e30f;
                sc[g][b] = v;
                mv = fmaxf(mv, v);
            }
        }
        #pragma unroll
        for (int o2 = 32; o2; o2 >>= 1) mv = fmaxf(mv, __shfl_xor(mv, o2));

        // ---- exp + l accumulation; stash p in LDS (dedup writers) ----
        float l_lane[NG] = {0.f, 0.f, 0.f, 0.f};
        #pragma unroll
        for (int b = 0; b < 8; ++b)
            #pragma unroll
            for (int g = 0; g < NG; ++g) {
                const float pr = __expf(sc[g][b] - mv);   // 0 for masked
                sc[g][b] = pr;
                l_lane[g] += pr;
            }
        if ((lane & 33) == 0) {               // lane = 2*t, t=0..15
            const int t = lane >> 1;
            #pragma unroll
            for (int g = 0; g < NG; ++g)
                #pragma unroll
                for (int b = 0; b < 8; ++b)
                    pw[g * WPT + b * 16 + t] = sc[g][b];
        }
        #pragma unroll
        for (int o2 = 32; o2; o2 >>= 1) {
            l_lane[0] += __shfl_xor(l_lane[0], o2);
            l_lane[1] += __shfl_xor(l_lane[1], o2);
            l_lane[2] += __shfl_xor(l_lane[2], o2);
            l_lane[3] += __shfl_xor(l_lane[3], o2);
        }   // 4x true sum (each token on 4 lanes)

        // ---- PV: 64 contiguous 1KB loads; p4 broadcast from LDS ----
        float acc[NG][8];
        #pragma unroll
        for (int g = 0; g < NG; ++g)
            #pragma unroll
            for (int sub = 0; sub < 8; ++sub) acc[g][sub] = 0.f;

        #pragma unroll 2
        for (int b = 0; b < 8; ++b) {
            float4 p4[NG];
            #pragma unroll
            for (int g = 0; g < NG; ++g)
                p4[g] = *(const float4*)&pw[g * WPT + b * 16 + (lane & 3) * 4];
            const int tlb = ctx - 1 - t0 - b * 16;
            if (tlb >= 0 && tlb < 16) {       // wave-uniform: new-token block
                const bool myl = (lane & 3) == (tlb >> 2);
                #pragma unroll
                for (int sub = 0; sub < 8; ++sub) {
                    float4 v4 = *(const float4*)(vbase[b] + sub * 256);
                    const float vnew = value[((size_t)s * KVH + kvh) * HD
                                             + sub * 16 + (lane >> 2)];
                    v4.x = (myl && (tlb & 3) == 0) ? vnew : v4.x;
                    v4.y = (myl && (tlb & 3) == 1) ? vnew : v4.y;
                    v4.z = (myl && (tlb & 3) == 2) ? vnew : v4.z;
                    v4.w = (myl && (tlb & 3) == 3) ? vnew : v4.w;
                    #pragma unroll
                    for (int g = 0; g < NG; ++g)
                        acc[g][sub] += p4[g].x * v4.x + p4[g].y * v4.y
                                     + p4[g].z * v4.z + p4[g].w * v4.w;
                }
            } else {
                #pragma unroll
                for (int sub = 0; sub < 8; ++sub) {
                    const float4 v4 = *(const float4*)(vbase[b] + sub * 256);
                    #pragma unroll
                    for (int g = 0; g < NG; ++g)
                        acc[g][sub] += p4[g].x * v4.x + p4[g].y * v4.y
                                     + p4[g].z * v4.z + p4[g].w * v4.w;
                }
            }
        }

        // ---- reduce token-quads, write record ----
        #pragma unroll
        for (int g = 0; g < NG; ++g)
            #pragma unroll
            for (int sub = 0; sub < 8; ++sub) {
                float a = acc[g][sub];
                a += __shfl_xor(a, 1);
                a += __shfl_xor(a, 2);
                acc[g][sub] = a;
            }

        float* rec = ws + (size_t)item * PSTRIDE;
        if ((lane & 3) == 0) {
            const int dd = lane >> 2;         // 0..15
            #pragma unroll
            for (int g = 0; g < NG; ++g)
                #pragma unroll
                for (int sub = 0; sub < 8; ++sub)
                    rec[g * HD + sub * 16 + dd] = acc[g][sub];
        }
        if (lane == 0) {
            #pragma unroll
            for (int g = 0; g < NG; ++g) rec[512 + g] = l_lane[g] * 0.25f;
            rec[516] = mv;
        }
    }
}

// Kernel 2: LSE-combine the <=32 partitions -> output. One (seq,kvh,g) per block.
__global__ __launch_bounds__(128) void pa_reduce_kernel(
    const float* __restrict__ ws,
    const int*   __restrict__ context_lens,
    float*       __restrict__ out)
{
    const int b    = blockIdx.x;        // ((s*KVH)+kvh)*NG + g
    const int g    = b & 3;
    const int pair = b >> 2;            // s*KVH + kvh
    const int s    = pair >> 3;
    const int kvh  = pair & 7;
    const int ctx  = context_lens[s];
    const int np   = (ctx + WPT - 1) / WPT;

    const int d = threadIdx.x;
    const float* base = ws + (size_t)pair * NCHUNK * PSTRIDE;

    float M = -1e30f;
    for (int p2 = 0; p2 < np; ++p2) M = fmaxf(M, base[p2 * PSTRIDE + 516]);

    float L = 0.f, acc = 0.f;
    for (int p2 = 0; p2 < np; ++p2) {
        const float* rec = base + p2 * PSTRIDE;
        const float w = __expf(rec[516] - M);
        L   += w * rec[512 + g];
        acc += w * rec[g * HD + d];
    }

    out[(size_t)s * (KVH * NG * HD) + (size_t)(kvh * NG + g) * HD + d] = acc / L;
}

extern "C" void kernel_launch(void* const* d_in, const int* in_sizes, int n_in,
                              void* d_out, int out_size, void* d_ws, size_t ws_size,
                              hipStream_t stream) {
    const float* query       = (const float*)d_in[0];
    const float* key         = (const float*)d_in[1];
    const float* value       = (const float*)d_in[2];
    const float* key_cache   = (const float*)d_in[3];
    const float* value_cache = (const float*)d_in[4];
    const int*   block_tables  = (const int*)d_in[5];
    const int*   context_lens  = (const int*)d_in[6];
    // d_in[7] slot_mapping unused: slot is derivable from context_lens + block_tables

    float* out = (float*)d_out;
    float* ws  = (float*)d_ws;   // records: 4096*520*4 = 8.52 MB, + 4 B counter
    unsigned int* counter = (unsigned int*)((char*)d_ws + REC_BYTES);

    hipMemsetAsync(counter, 0, sizeof(unsigned int), stream);
    pa_partial_kernel<<<NBLOCKS, 256, 0, stream>>>(
        query, key, value, key_cache, value_cache, block_tables, context_lens, ws, counter);
    pa_reduce_kernel<<<NSEQ * KVH * NG, 128, 0, stream>>>(ws, context_lens, out);
}